// Round 1
// baseline (1055.707 us; speedup 1.0000x reference)
//
#include <hip/hip_runtime.h>
#include <hip/hip_bf16.h>

// dims
#define B_ 8
#define S_ 2048
#define D_ 1024
#define H1_ 512
#define DH_ 128
#define DV_ 512
#define DOUT_ 512

typedef __bf16 bf16x8 __attribute__((ext_vector_type(8)));
typedef __bf16 bf16x4 __attribute__((ext_vector_type(4)));
typedef float  f32x4  __attribute__((ext_vector_type(4)));

// ---------------------------------------------------------------------------
// prep 1: W12T[h][d] = sum_j w1[d][j]*w2[j][h]  (and W46T from w4,w6)
// stored transposed (N x K, bf16) so GEMM B-frags are contiguous 16B loads.
// ---------------------------------------------------------------------------
__global__ __launch_bounds__(256) void prep_w12(
    const float* __restrict__ w1, const float* __restrict__ w2,
    const float* __restrict__ w4, const float* __restrict__ w6,
    __bf16* __restrict__ w12t, __bf16* __restrict__ w46t) {
  int tid = blockIdx.x * 256 + threadIdx.x;   // 131072 threads
  const float* wa; const float* wb; __bf16* o;
  if (blockIdx.y == 0) { wa = w1; wb = w2; o = w12t; }
  else                 { wa = w4; wb = w6; o = w46t; }
  int h = tid & 127;        // 0..127  (consecutive -> coalesced w2 reads)
  int d = tid >> 7;         // 0..1023
  float acc = 0.f;
  for (int j = 0; j < H1_; ++j)
    acc += wa[d * H1_ + j] * wb[j * DH_ + h];
  o[h * D_ + d] = (__bf16)acc;   // transposed store
}

// ---------------------------------------------------------------------------
// prep 2: w3T[n][d] = w3[d][n];  W7sT[n][k] = w7[k][n] + w7[k+512][n]
// ---------------------------------------------------------------------------
__global__ __launch_bounds__(256) void prep_w3_w7(
    const float* __restrict__ w3, const float* __restrict__ w7,
    __bf16* __restrict__ w3t, __bf16* __restrict__ w7st) {
  int tid = blockIdx.x * 256 + threadIdx.x;   // 786432 threads
  if (tid < D_ * DV_) {                        // 524288: transpose w3
    int n = tid & 511, d = tid >> 9;
    w3t[n * D_ + d] = (__bf16)w3[d * DV_ + n];
  } else {
    int t = tid - D_ * DV_;                    // 262144: fold+transpose w7
    int n = t & 511, kk = t >> 9;
    w7st[n * DV_ + kk] = (__bf16)(w7[kk * DOUT_ + n] + w7[(kk + DV_) * DOUT_ + n]);
  }
}

// ---------------------------------------------------------------------------
// bf16 MFMA GEMM: C(MxN) = A(MxK) @ B(KxN), B given transposed (BT: N x K bf16)
// A is fp32 or bf16 (converted to bf16 while staging into LDS); optional fused
// A = A1 + A2. Tile 128x128, BK=32, 256 threads = 2x2 waves, each wave 4x4
// MFMA tiles of 16x16x32. B-frags read directly from global (L2-resident
// weights), prefetched one K-iter ahead.
// M%128==0, N%128==0, K%32==0 assumed.
// ---------------------------------------------------------------------------
template <typename AT, typename OT, bool FUSE>
__global__ __launch_bounds__(256) void gemm_mfma(
    const AT* __restrict__ A1, const AT* __restrict__ A2,
    const __bf16* __restrict__ BT, OT* __restrict__ C,
    const int M, const int N, const int K) {
  __shared__ __bf16 As[128 * 40];   // row stride 40 bf16 (pad: bank-friendly)
  const int tid = threadIdx.x;
  const int mBase = blockIdx.x * 128;
  const int nBase = blockIdx.y * 128;
  const int wave = tid >> 6, lane = tid & 63;
  const int wr = wave >> 1, wc = wave & 1;       // 2x2 waves of 64x64
  const int l16 = lane & 15, quad = lane >> 4;

  f32x4 acc[4][4] = {};
  const int nb = nBase + wc * 64;

  bf16x8 bfr[4], bnx[4];
  for (int nt = 0; nt < 4; ++nt)
    bfr[nt] = *(const bf16x8*)(BT + (size_t)(nb + nt * 16 + l16) * K + quad * 8);

  for (int k0 = 0; k0 < K; k0 += 32) {
    // ---- stage A tile (128x32) fp32/bf16 -> bf16 LDS ----
    for (int i = 0; i < 4; ++i) {
      int ch = tid + 256 * i;            // 1024 chunks of 4 elems
      int row = ch >> 3, k4 = (ch & 7) << 2;
      size_t off = (size_t)(mBase + row) * K + k0 + k4;
      float f0, f1, f2, f3;
      if constexpr (sizeof(AT) == 4) {
        float4 v = *(const float4*)((const float*)A1 + off);
        f0 = v.x; f1 = v.y; f2 = v.z; f3 = v.w;
        if constexpr (FUSE) {
          float4 v2 = *(const float4*)((const float*)A2 + off);
          f0 += v2.x; f1 += v2.y; f2 += v2.z; f3 += v2.w;
        }
      } else {
        bf16x4 v = *(const bf16x4*)((const __bf16*)A1 + off);
        f0 = (float)v[0]; f1 = (float)v[1]; f2 = (float)v[2]; f3 = (float)v[3];
        if constexpr (FUSE) {
          bf16x4 v2 = *(const bf16x4*)((const __bf16*)A2 + off);
          f0 += (float)v2[0]; f1 += (float)v2[1]; f2 += (float)v2[2]; f3 += (float)v2[3];
        }
      }
      bf16x4 w; w[0] = (__bf16)f0; w[1] = (__bf16)f1; w[2] = (__bf16)f2; w[3] = (__bf16)f3;
      *(bf16x4*)&As[row * 40 + k4] = w;
    }
    __syncthreads();

    // prefetch next B frags (global, overlaps with MFMA below)
    if (k0 + 32 < K)
      for (int nt = 0; nt < 4; ++nt)
        bnx[nt] = *(const bf16x8*)(BT + (size_t)(nb + nt * 16 + l16) * K + (k0 + 32) + quad * 8);

    bf16x8 afr[4];
    for (int mt = 0; mt < 4; ++mt)
      afr[mt] = *(bf16x8*)&As[(wr * 64 + mt * 16 + l16) * 40 + quad * 8];

    for (int mt = 0; mt < 4; ++mt)
      for (int nt = 0; nt < 4; ++nt)
        acc[mt][nt] = __builtin_amdgcn_mfma_f32_16x16x32_bf16(afr[mt], bfr[nt], acc[mt][nt], 0, 0, 0);
    __syncthreads();

    for (int nt = 0; nt < 4; ++nt) bfr[nt] = bnx[nt];
  }

  // epilogue: D layout col=lane&15, row=quad*4+reg  [verified m89/m91]
  for (int mt = 0; mt < 4; ++mt) {
    int rowb = mBase + wr * 64 + mt * 16 + quad * 4;
    for (int nt = 0; nt < 4; ++nt) {
      int col = nBase + wc * 64 + nt * 16 + l16;
      for (int r = 0; r < 4; ++r)
        C[(size_t)(rowb + r) * N + col] = (OT)acc[mt][nt][r];
    }
  }
}

// ---------------------------------------------------------------------------
// causal flash attention, fp32 accumulate. q2,k3 bf16 (B,S,128), v fp32
// (B,S,512), out bf16 (B,S,512). Block: 256 thr, TQ=32 queries, TK=16 keys.
// ---------------------------------------------------------------------------
__global__ __launch_bounds__(256) void flash_attn(
    const __bf16* __restrict__ q2, const __bf16* __restrict__ k3,
    const float* __restrict__ v, __bf16* __restrict__ out) {
  __shared__ float Qs[32 * 132];
  __shared__ float Ks[16 * 132];
  __shared__ float Vs[16 * 512];
  __shared__ float Ss[32 * 17];
  __shared__ float al[32];
  __shared__ float ll[32];

  const int b = blockIdx.y, qt = blockIdx.x;
  const int q0 = qt * 32;
  const int tid = threadIdx.x;
  const __bf16* q2b = q2 + (size_t)b * S_ * DH_;
  const __bf16* k3b = k3 + (size_t)b * S_ * DH_;
  const float*  vb  = v  + (size_t)b * S_ * DV_;

  // stage Q tile (32 x 128)
  for (int i = 0; i < 4; ++i) {
    int ch = tid + 256 * i;                 // 1024 chunks of 4
    int row = ch >> 5, k4 = (ch & 31) << 2;
    bf16x4 vq = *(const bf16x4*)(q2b + (size_t)(q0 + row) * DH_ + k4);
    *(float4*)&Qs[row * 132 + k4] =
        make_float4((float)vq[0], (float)vq[1], (float)vq[2], (float)vq[3]);
  }

  float m_r = -INFINITY, l_r = 0.f;         // per-row state, threads 0..31
  f32x4 acc[4][4] = {};                     // 4 rows x 4 float4 (cols cg*4+128j)
  const int r_sc = tid >> 3, kk2 = tid & 7; // score mapping: 2 scores/thread
  const int rg = tid >> 5, cg = tid & 31;   // PV mapping: rows rg*4+i
  const float scale = 0.08838834764831845f; // 1/sqrt(128)

  const int ktMax = (q0 + 31) >> 4;
  for (int kt = 0; kt <= ktMax; ++kt) {
    const int k0 = kt * 16;
    // ---- stage K (16x128) ----
    for (int i = 0; i < 2; ++i) {
      int ch = tid + 256 * i;               // 512 chunks of 4
      int row = ch >> 5, k4 = (ch & 31) << 2;
      bf16x4 vk = *(const bf16x4*)(k3b + (size_t)(k0 + row) * DH_ + k4);
      *(float4*)&Ks[row * 132 + k4] =
          make_float4((float)vk[0], (float)vk[1], (float)vk[2], (float)vk[3]);
    }
    // ---- stage V (16x512) ----
    for (int i = 0; i < 8; ++i) {
      int ch = tid + 256 * i;               // 2048 float4 chunks
      int row = ch >> 7, c4 = (ch & 127) << 2;
      *(float4*)&Vs[row * 512 + c4] = *(const float4*)(vb + (size_t)(k0 + row) * DV_ + c4);
    }
    __syncthreads();

    // ---- scores: thread -> row r_sc, keys kk2 and kk2+8 ----
    {
      float s0 = 0.f, s1 = 0.f;
      for (int d4 = 0; d4 < 32; ++d4) {
        float4 qv  = *(float4*)&Qs[r_sc * 132 + d4 * 4];
        float4 k0v = *(float4*)&Ks[kk2 * 132 + d4 * 4];
        float4 k1v = *(float4*)&Ks[(kk2 + 8) * 132 + d4 * 4];
        s0 += qv.x * k0v.x + qv.y * k0v.y + qv.z * k0v.z + qv.w * k0v.w;
        s1 += qv.x * k1v.x + qv.y * k1v.y + qv.z * k1v.z + qv.w * k1v.w;
      }
      s0 *= scale; s1 *= scale;
      int qi = q0 + r_sc;
      if (k0 + kk2 > qi)     s0 = -INFINITY;
      if (k0 + kk2 + 8 > qi) s1 = -INFINITY;
      Ss[r_sc * 17 + kk2]     = s0;
      Ss[r_sc * 17 + kk2 + 8] = s1;
    }
    __syncthreads();

    // ---- online softmax (one thread per row) ----
    if (tid < 32) {
      float mx = -INFINITY;
      for (int kk = 0; kk < 16; ++kk) mx = fmaxf(mx, Ss[tid * 17 + kk]);
      float mn = fmaxf(m_r, mx);
      float alpha = __expf(m_r - mn);       // first tile: exp(-inf)=0
      float lsum = 0.f;
      for (int kk = 0; kk < 16; ++kk) {
        float p = __expf(Ss[tid * 17 + kk] - mn);
        Ss[tid * 17 + kk] = p;
        lsum += p;
      }
      l_r = l_r * alpha + lsum;
      m_r = mn;
      al[tid] = alpha;
    }
    __syncthreads();

    // ---- rescale + PV accumulate ----
    {
      float a0 = al[rg * 4 + 0], a1 = al[rg * 4 + 1];
      float a2 = al[rg * 4 + 2], a3 = al[rg * 4 + 3];
      for (int j = 0; j < 4; ++j) {
        acc[0][j] *= a0; acc[1][j] *= a1; acc[2][j] *= a2; acc[3][j] *= a3;
      }
      for (int kk = 0; kk < 16; ++kk) {
        float p0 = Ss[(rg * 4 + 0) * 17 + kk];
        float p1 = Ss[(rg * 4 + 1) * 17 + kk];
        float p2 = Ss[(rg * 4 + 2) * 17 + kk];
        float p3 = Ss[(rg * 4 + 3) * 17 + kk];
        for (int j = 0; j < 4; ++j) {
          f32x4 vv = *(f32x4*)&Vs[kk * 512 + cg * 4 + j * 128];
          acc[0][j] += p0 * vv; acc[1][j] += p1 * vv;
          acc[2][j] += p2 * vv; acc[3][j] += p3 * vv;
        }
      }
    }
    __syncthreads();
  }

  // ---- epilogue: divide by l, write bf16 ----
  if (tid < 32) ll[tid] = l_r;
  __syncthreads();
  for (int i = 0; i < 4; ++i) {
    int row = rg * 4 + i;
    float inv = 1.0f / ll[row];
    __bf16* op = out + ((size_t)b * S_ + q0 + row) * DV_;
    for (int j = 0; j < 4; ++j) {
      f32x4 o = acc[i][j] * inv;
      bf16x4 ob; ob[0] = (__bf16)o[0]; ob[1] = (__bf16)o[1];
      ob[2] = (__bf16)o[2]; ob[3] = (__bf16)o[3];
      *(bf16x4*)(op + cg * 4 + j * 128) = ob;
    }
  }
}

// ---------------------------------------------------------------------------
extern "C" void kernel_launch(void* const* d_in, const int* in_sizes, int n_in,
                              void* d_out, int out_size, void* d_ws, size_t ws_size,
                              hipStream_t stream) {
  const float* q  = (const float*)d_in[0];
  const float* k  = (const float*)d_in[1];
  const float* v  = (const float*)d_in[2];
  const float* w1 = (const float*)d_in[3];
  const float* w2 = (const float*)d_in[4];
  const float* w3 = (const float*)d_in[5];
  const float* w4 = (const float*)d_in[6];
  const float* w6 = (const float*)d_in[7];
  const float* w7 = (const float*)d_in[8];
  float* out = (float*)d_out;

  char* ws = (char*)d_ws;
  __bf16* W12T = (__bf16*)(ws + 0);          //  128x1024 bf16  256KB
  __bf16* W46T = (__bf16*)(ws + 262144);     //  128x1024 bf16  256KB
  __bf16* w3T  = (__bf16*)(ws + 524288);     //  512x1024 bf16    1MB
  __bf16* W7sT = (__bf16*)(ws + 1572864);    //  512x512  bf16  512KB
  __bf16* q2   = (__bf16*)(ws + 2097152);    // 16384x128 bf16    4MB
  __bf16* k3   = (__bf16*)(ws + 6291456);    // 16384x128 bf16    4MB
  __bf16* q3   = (__bf16*)(ws + 10485760);   // 16384x512 bf16   16MB
  __bf16* attn = (__bf16*)(ws + 27262976);   // 16384x512 bf16   16MB
  // total ws use: 44040192 bytes (~42 MB)

  prep_w12<<<dim3(512, 2), 256, 0, stream>>>(w1, w2, w4, w6, W12T, W46T);
  prep_w3_w7<<<dim3(3072), 256, 0, stream>>>(w3, w7, w3T, W7sT);

  // q2 = q @ W12   (M=16384, N=128, K=1024)
  gemm_mfma<float, __bf16, false><<<dim3(128, 1), 256, 0, stream>>>(
      q, (const float*)nullptr, W12T, q2, 16384, 128, 1024);
  // k3 = k @ W46
  gemm_mfma<float, __bf16, false><<<dim3(128, 1), 256, 0, stream>>>(
      k, (const float*)nullptr, W46T, k3, 16384, 128, 1024);
  // q3 = q @ w3    (N=512, K=1024)
  gemm_mfma<float, __bf16, false><<<dim3(128, 4), 256, 0, stream>>>(
      q, (const float*)nullptr, w3T, q3, 16384, 512, 1024);

  // causal attention
  flash_attn<<<dim3(64, 8), 256, 0, stream>>>(q2, k3, v, attn);

  // out = (attn + q3) @ W7s   (N=512, K=512), fp32 output
  gemm_mfma<__bf16, float, true><<<dim3(128, 4), 256, 0, stream>>>(
      attn, q3, W7sT, out, 16384, 512, 512);
}

// Round 2
// 686.855 us; speedup vs baseline: 1.5370x; 1.5370x over previous
//
#include <hip/hip_runtime.h>
#include <hip/hip_bf16.h>

// dims
#define B_ 8
#define S_ 2048
#define D_ 1024
#define H1_ 512
#define DH_ 128
#define DV_ 512
#define DOUT_ 512

typedef __bf16 bf16x8 __attribute__((ext_vector_type(8)));
typedef __bf16 bf16x4 __attribute__((ext_vector_type(4)));
typedef float  f32x4  __attribute__((ext_vector_type(4)));

#define SM_SCALE 0.08838834764831845f  // 1/sqrt(128), folded into W12T

// ---------------------------------------------------------------------------
// prep 1: W12T[h][d] = scale * sum_j w1[d][j]*w2[j][h]; W46T likewise (no scale)
// ---------------------------------------------------------------------------
__global__ __launch_bounds__(256) void prep_w12(
    const float* __restrict__ w1, const float* __restrict__ w2,
    const float* __restrict__ w4, const float* __restrict__ w6,
    __bf16* __restrict__ w12t, __bf16* __restrict__ w46t) {
  int tid = blockIdx.x * 256 + threadIdx.x;   // 131072 threads
  const float* wa; const float* wb; __bf16* o; float sc;
  if (blockIdx.y == 0) { wa = w1; wb = w2; o = w12t; sc = SM_SCALE; }
  else                 { wa = w4; wb = w6; o = w46t; sc = 1.0f; }
  int h = tid & 127;        // 0..127
  int d = tid >> 7;         // 0..1023
  float acc = 0.f;
  for (int j = 0; j < H1_; ++j)
    acc += wa[d * H1_ + j] * wb[j * DH_ + h];
  o[h * D_ + d] = (__bf16)(acc * sc);   // transposed store
}

// ---------------------------------------------------------------------------
// prep 2: w3T[n][d] = w3[d][n];  W7sT[n][k] = w7[k][n] + w7[k+512][n]
// ---------------------------------------------------------------------------
__global__ __launch_bounds__(256) void prep_w3_w7(
    const float* __restrict__ w3, const float* __restrict__ w7,
    __bf16* __restrict__ w3t, __bf16* __restrict__ w7st) {
  int tid = blockIdx.x * 256 + threadIdx.x;   // 786432 threads
  if (tid < D_ * DV_) {
    int n = tid & 511, d = tid >> 9;
    w3t[n * D_ + d] = (__bf16)w3[d * DV_ + n];
  } else {
    int t = tid - D_ * DV_;
    int n = t & 511, kk = t >> 9;
    w7st[n * DV_ + kk] = (__bf16)(w7[kk * DOUT_ + n] + w7[(kk + DV_) * DOUT_ + n]);
  }
}

// ---------------------------------------------------------------------------
// prep 3: VT[b][n][t] = (bf16) v[b][t][n]   (32x32 LDS tile transpose)
// ---------------------------------------------------------------------------
__global__ __launch_bounds__(256) void prep_vt(
    const float* __restrict__ v, __bf16* __restrict__ vt) {
  __shared__ float tile[32][33];
  int b = blockIdx.z;
  int t0 = blockIdx.x * 32, n0 = blockIdx.y * 32;
  int tx = threadIdx.x & 31, ty = threadIdx.x >> 5;  // 32x8
  const float* vb = v + (size_t)b * S_ * DV_;
  for (int i = 0; i < 4; ++i)
    tile[ty + 8 * i][tx] = vb[(size_t)(t0 + ty + 8 * i) * DV_ + n0 + tx];
  __syncthreads();
  __bf16* vtb = vt + (size_t)b * DV_ * S_;
  for (int i = 0; i < 4; ++i)
    vtb[(size_t)(n0 + ty + 8 * i) * S_ + t0 + tx] = (__bf16)tile[tx][ty + 8 * i];
}

// ---------------------------------------------------------------------------
// bf16 MFMA GEMM (unchanged from R1, passed): C = A @ B, BT given N x K.
// ---------------------------------------------------------------------------
template <typename AT, typename OT, bool FUSE>
__global__ __launch_bounds__(256) void gemm_mfma(
    const AT* __restrict__ A1, const AT* __restrict__ A2,
    const __bf16* __restrict__ BT, OT* __restrict__ C,
    const int M, const int N, const int K) {
  __shared__ __bf16 As[128 * 40];
  const int tid = threadIdx.x;
  const int mBase = blockIdx.x * 128;
  const int nBase = blockIdx.y * 128;
  const int wave = tid >> 6, lane = tid & 63;
  const int wr = wave >> 1, wc = wave & 1;
  const int l16 = lane & 15, quad = lane >> 4;

  f32x4 acc[4][4] = {};
  const int nb = nBase + wc * 64;

  bf16x8 bfr[4], bnx[4];
  for (int nt = 0; nt < 4; ++nt)
    bfr[nt] = *(const bf16x8*)(BT + (size_t)(nb + nt * 16 + l16) * K + quad * 8);

  for (int k0 = 0; k0 < K; k0 += 32) {
    for (int i = 0; i < 4; ++i) {
      int ch = tid + 256 * i;
      int row = ch >> 3, k4 = (ch & 7) << 2;
      size_t off = (size_t)(mBase + row) * K + k0 + k4;
      float f0, f1, f2, f3;
      if constexpr (sizeof(AT) == 4) {
        float4 vv = *(const float4*)((const float*)A1 + off);
        f0 = vv.x; f1 = vv.y; f2 = vv.z; f3 = vv.w;
        if constexpr (FUSE) {
          float4 v2 = *(const float4*)((const float*)A2 + off);
          f0 += v2.x; f1 += v2.y; f2 += v2.z; f3 += v2.w;
        }
      } else {
        bf16x4 vv = *(const bf16x4*)((const __bf16*)A1 + off);
        f0 = (float)vv[0]; f1 = (float)vv[1]; f2 = (float)vv[2]; f3 = (float)vv[3];
        if constexpr (FUSE) {
          bf16x4 v2 = *(const bf16x4*)((const __bf16*)A2 + off);
          f0 += (float)v2[0]; f1 += (float)v2[1]; f2 += (float)v2[2]; f3 += (float)v2[3];
        }
      }
      bf16x4 w; w[0] = (__bf16)f0; w[1] = (__bf16)f1; w[2] = (__bf16)f2; w[3] = (__bf16)f3;
      *(bf16x4*)&As[row * 40 + k4] = w;
    }
    __syncthreads();

    if (k0 + 32 < K)
      for (int nt = 0; nt < 4; ++nt)
        bnx[nt] = *(const bf16x8*)(BT + (size_t)(nb + nt * 16 + l16) * K + (k0 + 32) + quad * 8);

    bf16x8 afr[4];
    for (int mt = 0; mt < 4; ++mt)
      afr[mt] = *(bf16x8*)&As[(wr * 64 + mt * 16 + l16) * 40 + quad * 8];

    for (int mt = 0; mt < 4; ++mt)
      for (int nt = 0; nt < 4; ++nt)
        acc[mt][nt] = __builtin_amdgcn_mfma_f32_16x16x32_bf16(afr[mt], bfr[nt], acc[mt][nt], 0, 0, 0);
    __syncthreads();

    for (int nt = 0; nt < 4; ++nt) bfr[nt] = bnx[nt];
  }

  for (int mt = 0; mt < 4; ++mt) {
    int rowb = mBase + wr * 64 + mt * 16 + quad * 4;
    for (int nt = 0; nt < 4; ++nt) {
      int col = nBase + wc * 64 + nt * 16 + l16;
      for (int r = 0; r < 4; ++r)
        C[(size_t)(rowb + r) * N + col] = (OT)acc[mt][nt][r];
    }
  }
}

// ---------------------------------------------------------------------------
// MFMA flash attention, wave-autonomous (1 wave / block, no __syncthreads).
// Per wave: 16 query rows. Per iter: 32 keys.
//   S^T = K3 @ Q2^T  (2 m-tiles x 4 k-chunks = 8 MFMAs)  [scale pre-folded]
//   online softmax: alpha uniform per lane (col = qrow = l16)
//   P -> LDS (bf16, [qrow][key], stride 80B) -> B-frag (1 ds_read_b128)
//   out^T = VT @ P   (32 m-tiles = 32 MFMAs, A-frags 16B from global VT)
// ---------------------------------------------------------------------------
__global__ __launch_bounds__(64) void flash_attn_mfma(
    const __bf16* __restrict__ q2, const __bf16* __restrict__ k3,
    const __bf16* __restrict__ vt, __bf16* __restrict__ attn) {
  __shared__ __bf16 Pb[16 * 40];   // 16 rows x 80B stride
  const int lane = threadIdx.x;
  const int l16 = lane & 15, quad = lane >> 4;
  const int bx = blockIdx.x;            // 0..1023
  const int b = bx >> 7;                // batch-major: co-resident blocks share k3/VT
  const int tile = 127 - (bx & 127);    // big tiles dispatched first within batch
  const int q0 = tile * 16;

  const __bf16* q2b = q2 + ((size_t)b * S_ + q0) * DH_;
  const __bf16* k3b = k3 + (size_t)b * S_ * DH_;
  const __bf16* vtb = vt + (size_t)b * DV_ * S_;

  // Q B-frags: lane holds Q2[qrow=l16][dh=c*32+quad*8 ..+7]
  bf16x8 qf[4];
  for (int c = 0; c < 4; ++c)
    qf[c] = *(const bf16x8*)(q2b + l16 * DH_ + c * 32 + quad * 8);

  f32x4 acc[32] = {};                   // out^T: vcol = mt*16+quad*4+r, qrow = l16
  float m = -1e30f, l = 0.f;
  const int qrow = q0 + l16;

  const int nkt = (q0 + 16 + 31) >> 5;  // ceil((q0+16)/32)
  for (int kt = 0; kt < nkt; ++kt) {
    const int k0 = kt * 32;

    // ---- S^T (32 keys x 16 qrows) ----
    f32x4 st[2] = {};
    for (int h = 0; h < 2; ++h) {
      const __bf16* kp = k3b + (size_t)(k0 + h * 16 + l16) * DH_;
      for (int c = 0; c < 4; ++c) {
        bf16x8 kf = *(const bf16x8*)(kp + c * 32 + quad * 8);
        st[h] = __builtin_amdgcn_mfma_f32_16x16x32_bf16(kf, qf[c], st[h], 0, 0, 0);
      }
    }

    // ---- causal mask + online softmax ----
    float mloc = -1e30f;
    for (int h = 0; h < 2; ++h)
      for (int r = 0; r < 4; ++r) {
        int key = k0 + h * 16 + quad * 4 + r;
        float s = (key <= qrow) ? st[h][r] : -1e30f;
        st[h][r] = s;
        mloc = fmaxf(mloc, s);
      }
    mloc = fmaxf(mloc, __shfl_xor(mloc, 16));
    mloc = fmaxf(mloc, __shfl_xor(mloc, 32));
    float mnew = fmaxf(m, mloc);
    float alpha = __expf(m - mnew);
    float lloc = 0.f;
    bf16x4 pb[2];
    for (int h = 0; h < 2; ++h)
      for (int r = 0; r < 4; ++r) {
        float p = __expf(st[h][r] - mnew);
        lloc += p;
        pb[h][r] = (__bf16)p;
      }
    lloc += __shfl_xor(lloc, 16);
    lloc += __shfl_xor(lloc, 32);
    l = l * alpha + lloc;
    m = mnew;

    // ---- P -> LDS [qrow][key] (b64 writes: keys quad*4..+3) ----
    for (int h = 0; h < 2; ++h)
      *(bf16x4*)((char*)Pb + l16 * 80 + (h * 16 + quad * 4) * 2) = pb[h];

    // rescale accumulator (skip when no row's max moved)
    if (__any(alpha < 1.f))
      for (int mt = 0; mt < 32; ++mt) acc[mt] *= alpha;

    // ---- PV: B-frag = P[key=quad*8+j][qrow=l16] ----
    bf16x8 pf = *(bf16x8*)((char*)Pb + l16 * 80 + quad * 16);
    for (int mt = 0; mt < 32; ++mt) {
      bf16x8 vf = *(const bf16x8*)(vtb + (size_t)(mt * 16 + l16) * S_ + k0 + quad * 8);
      acc[mt] = __builtin_amdgcn_mfma_f32_16x16x32_bf16(vf, pf, acc[mt], 0, 0, 0);
    }
  }

  // ---- epilogue: out[qrow][vcol] = acc/l ----
  float inv = 1.0f / l;
  __bf16* op = attn + ((size_t)b * S_ + q0 + l16) * DV_;
  for (int mt = 0; mt < 32; ++mt) {
    bf16x4 ob;
    for (int r = 0; r < 4; ++r) ob[r] = (__bf16)(acc[mt][r] * inv);
    *(bf16x4*)(op + mt * 16 + quad * 4) = ob;
  }
}

// ---------------------------------------------------------------------------
extern "C" void kernel_launch(void* const* d_in, const int* in_sizes, int n_in,
                              void* d_out, int out_size, void* d_ws, size_t ws_size,
                              hipStream_t stream) {
  const float* q  = (const float*)d_in[0];
  const float* k  = (const float*)d_in[1];
  const float* v  = (const float*)d_in[2];
  const float* w1 = (const float*)d_in[3];
  const float* w2 = (const float*)d_in[4];
  const float* w3 = (const float*)d_in[5];
  const float* w4 = (const float*)d_in[6];
  const float* w6 = (const float*)d_in[7];
  const float* w7 = (const float*)d_in[8];
  float* out = (float*)d_out;

  char* ws = (char*)d_ws;
  __bf16* W12T = (__bf16*)(ws + 0);          //  128x1024 bf16  256KB
  __bf16* W46T = (__bf16*)(ws + 262144);     //  128x1024 bf16  256KB
  __bf16* w3T  = (__bf16*)(ws + 524288);     //  512x1024 bf16    1MB
  __bf16* W7sT = (__bf16*)(ws + 1572864);    //  512x512  bf16  512KB
  __bf16* q2   = (__bf16*)(ws + 2097152);    // 16384x128 bf16    4MB
  __bf16* k3   = (__bf16*)(ws + 6291456);    // 16384x128 bf16    4MB
  __bf16* q3   = (__bf16*)(ws + 10485760);   // 16384x512 bf16   16MB
  __bf16* attn = (__bf16*)(ws + 27262976);   // 16384x512 bf16   16MB
  __bf16* VT   = (__bf16*)(ws + 44040192);   // 8x512x2048 bf16  16MB
  // total ws use: ~58MB

  prep_w12<<<dim3(512, 2), 256, 0, stream>>>(w1, w2, w4, w6, W12T, W46T);
  prep_w3_w7<<<dim3(3072), 256, 0, stream>>>(w3, w7, w3T, W7sT);
  prep_vt<<<dim3(64, 16, 8), 256, 0, stream>>>(v, VT);

  gemm_mfma<float, __bf16, false><<<dim3(128, 1), 256, 0, stream>>>(
      q, (const float*)nullptr, W12T, q2, 16384, 128, 1024);
  gemm_mfma<float, __bf16, false><<<dim3(128, 1), 256, 0, stream>>>(
      k, (const float*)nullptr, W46T, k3, 16384, 128, 1024);
  gemm_mfma<float, __bf16, false><<<dim3(128, 4), 256, 0, stream>>>(
      q, (const float*)nullptr, w3T, q3, 16384, 512, 1024);

  flash_attn_mfma<<<dim3(1024), 64, 0, stream>>>(q2, k3, VT, attn);

  gemm_mfma<__bf16, float, true><<<dim3(128, 4), 256, 0, stream>>>(
      attn, q3, W7sT, out, 16384, 512, 512);
}